// Round 9
// baseline (644.639 us; speedup 1.0000x reference)
//
#include <hip/hip_runtime.h>
#include <hip/hip_cooperative_groups.h>
#include <math.h>

namespace cg = cooperative_groups;

#define Bb 8
#define Nn 64
#define Ff 32
#define Tt 4
#define OUTn 128
#define NPAIR 2016   // 64*63/2 lower-triangle pairs (i>j)

struct MegaArgs {
  const float *x, *A, *w_z, *w_c, *u_z, *u_c, *b_z, *b_c;
  const float *u_node, *u_msg, *lin_w, *lin_b;
  float *out;
  float *wzxb, *wcxb, *mf0, *mf1, *nrm0, *nrm1, *unfmax, *wbmax, *enc;
};

__device__ __forceinline__ float sigmoidf_(float x){ return 1.0f/(1.0f+expf(-x)); }

__device__ __forceinline__ void p2ij(int p, int& i, int& j){
  int ii = (int)((1.0f + sqrtf(1.0f + 8.0f*(float)p)) * 0.5f);
  while (ii*(ii-1)/2 > p) --ii;
  while ((ii+1)*ii/2 <= p) ++ii;
  i = ii; j = p - ii*(ii-1)/2;
}

// sequential-order fp32 dot (bit-identical to the validated round-0 ordering;
// the floor(sigmoid) gate is discontinuous -> this order must not change)
__device__ __forceinline__ float dot32(const float4* __restrict__ u, const float* __restrict__ v){
  const float4* v4 = (const float4*)v;
  float d = 0.f;
#pragma unroll
  for (int q=0;q<8;++q){
    float4 a=u[q], b=v4[q];
    d = fmaf(a.x,b.x,d); d = fmaf(a.y,b.y,d);
    d = fmaf(a.z,b.z,d); d = fmaf(a.w,b.w,d);
  }
  return d;
}

#define VCE(arr,g) ((g&3)==0 ? arr[(g)>>2].x : (g&3)==1 ? arr[(g)>>2].y : \
                    (g&3)==2 ? arr[(g)>>2].z : arr[(g)>>2].w)

__global__ __launch_bounds__(256, 4) void mega(MegaArgs a) {
  cg::grid_group grid = cg::this_grid();
  const int tid = threadIdx.x;
  const int bid = blockIdx.x;
  const int nblk = gridDim.x;
  const int w = tid >> 6;        // wave in block
  const int l = tid & 63;        // lane
  const int f = l & 31, h = l >> 5;
  const int h32 = l & 32;
  const int gw = bid*4 + w;      // global wave id
  const int ngw = nblk*4;

  __shared__ __align__(16) float xP[4][Bb][Ff];
  __shared__ __align__(16) float valP[4][2][Bb][Ff];
  __shared__ __align__(16) float Mc[Nn][Ff];
  __shared__ __align__(16) float aggP[8][Ff];
  __shared__ __align__(16) float aggL[Ff];
  __shared__ __align__(16) float vecF[4][2][Ff];
  __shared__ float normC[Nn];
  __shared__ int nbrL[Nn];
  __shared__ int jlistL[32], jslotL[32];
  __shared__ float nmaxL;
  __shared__ int nnL, jcL;

  // ================= Phase P: precompute (one pair per wave) =================
  for (int p = gw; p < NPAIR; p += ngw) {
    int i, j; p2ij(p, i, j);
    for (int q = l; q < Bb*Ff; q += 64)
      xP[w][q>>5][q&31] = a.x[((q>>5)*Nn + i)*Ff + (q&31)];
    const float* W = h ? a.w_c : a.w_z;
    const float4* w4 = (const float4*)&W[(((size_t)i*Nn + j)*Ff + f)*Ff];
    float4 wr[8];
#pragma unroll
    for (int q=0;q<8;++q) wr[q]=w4[q];
    float bias = h ? a.b_c[f] : a.b_z[f];
    float* dst = h ? a.wcxb : a.wzxb;
#pragma unroll
    for (int b=0;b<Bb;++b){
      float v = dot32(wr, xP[w][b]) + bias;
      dst[((size_t)(b*Nn + i)*Nn + j)*Ff + f] = v;
      valP[w][h][b][f] = v;
      if (h == 0) {          // wbmax[p,b] = max_f wzxb (scalar screen input)
        float wm = v;
        wm = fmaxf(wm, __shfl_xor(wm,1));  wm = fmaxf(wm, __shfl_xor(wm,2));
        wm = fmaxf(wm, __shfl_xor(wm,4));  wm = fmaxf(wm, __shfl_xor(wm,8));
        wm = fmaxf(wm, __shfl_xor(wm,16));
        if (f == 0) a.wbmax[p*8 + b] = wm;
      }
    }
    // t=0: m_full0 = sigmoid(wzxb)*tanh(wcxb)  (bit-exact; M=0 at t=0)
#pragma unroll
    for (int b=0;b<Bb;++b){
      float mfv = sigmoidf_(valP[w][0][b][f]) * tanhf(valP[w][1][b][f]);
      if (h == 0) a.mf0[((size_t)(b*Nn + i)*Nn + j)*Ff + f] = mfv;
      float ss = mfv*mfv;
      ss += __shfl_xor(ss,1); ss += __shfl_xor(ss,2); ss += __shfl_xor(ss,4);
      ss += __shfl_xor(ss,8); ss += __shfl_xor(ss,16);
      if (l == 0) a.nrm0[p*8 + b] = sqrtf(ss);
    }
    if (h == 0) {            // unfmax[p] = max_f ||u_z[i,j,f,:]||
      const float4* u4 = (const float4*)&a.u_z[(((size_t)i*Nn + j)*Ff + f)*Ff];
      float ss = 0.f;
#pragma unroll
      for (int q=0;q<8;++q){
        float4 v = u4[q];
        ss = fmaf(v.x,v.x,ss); ss = fmaf(v.y,v.y,ss);
        ss = fmaf(v.z,v.z,ss); ss = fmaf(v.w,v.w,ss);
      }
      ss = fmaxf(ss, __shfl_xor(ss,1));  ss = fmaxf(ss, __shfl_xor(ss,2));
      ss = fmaxf(ss, __shfl_xor(ss,4));  ss = fmaxf(ss, __shfl_xor(ss,8));
      ss = fmaxf(ss, __shfl_xor(ss,16));
      if (f == 0) a.unfmax[p] = sqrtf(ss);
    }
  }
  __threadfence();
  grid.sync();

  // ================= Phases E1..E3: MP iterations =================
  const float* mfR = a.mf0;  const float* nrR = a.nrm0;
  float* mfW = a.mf1;        float* nrW = a.nrm1;
  for (int t = 1; t < Tt; ++t) {
    for (int task = bid; task < Bb*Nn*2; task += nblk) {
      int b  = task >> 7;
      int i  = (task >> 1) & 63;
      int jh = task & 1;
      __syncthreads();   // LDS reuse guard across tasks
      if (tid < 64) {
        float av = a.A[(b*Nn + i)*Nn + tid];
        bool e = (av != 0.0f);
        unsigned long long m = __ballot(e);
        int rank = __popcll(m & ((1ull << tid) - 1ull));
        float nk = 0.f;
        if (e) {
          int k = tid;
          int hi = i > k ? i : k, lo = i > k ? k : i;
          nk = nrR[(hi*(hi-1)/2 + lo)*8 + b];
          nbrL[rank] = k;
          normC[rank] = nk;
        }
        float mx = e ? nk : 0.f;
        mx = fmaxf(mx, __shfl_xor(mx,1));  mx = fmaxf(mx, __shfl_xor(mx,2));
        mx = fmaxf(mx, __shfl_xor(mx,4));  mx = fmaxf(mx, __shfl_xor(mx,8));
        mx = fmaxf(mx, __shfl_xor(mx,16)); mx = fmaxf(mx, __shfl_xor(mx,32));
        bool ej = e && (tid < i);
        unsigned long long mj = __ballot(ej);
        if (ej) {
          int r = __popcll(mj & ((1ull << tid) - 1ull));
          if ((r & 1) == jh) { jlistL[r >> 1] = tid; jslotL[r >> 1] = rank; }
        }
        if (tid == 0) {
          nnL = __popcll(m);
          jcL = (__popcll(mj) + 1 - jh) >> 1;
          nmaxL = mx;
        }
      }
      __syncthreads();
      int nn = nnL, jc = jcL;
      float nmx = nmaxL;
      if (jc == 0) continue;

      // stage compact M rows (ascending k)
      for (int q = tid; q < nn*Ff; q += 256) {
        int s = q >> 5, ff = q & 31;
        int k = nbrL[s];
        int hi = i > k ? i : k, lo = i > k ? k : i;
        Mc[s][ff] = mfR[((size_t)(b*Nn + hi)*Nn + lo)*Ff + ff];
      }
      __syncthreads();
      // parallel 8-chunk agg (ascending within+across chunks; zero-chunks exact)
      {
        int c = tid >> 5, ff = tid & 31;
        float ps = 0.f;
        int s0 = c*8, s1 = s0 + 8 < nn ? s0 + 8 : nn;
        for (int s = s0; s < s1; ++s) ps += Mc[s][ff];
        aggP[c][ff] = ps;
      }
      __syncthreads();
      if (tid < 32) {
        float acc = 0.f;
#pragma unroll
        for (int c = 0; c < 8; ++c) acc += aggP[c][tid];
        aggL[tid] = acc;
      }
      __syncthreads();

      // j-rounds: 8 half-waves, one j each; no barriers (shuffle-only epilogue)
      int nr = (jc + 7) >> 3;
      for (int r = 0; r < nr; ++r) {
        int slot = (tid >> 5) + r*8;
        bool act = slot < jc;
        int j = jlistL[act ? slot : 0];
        int jslot = jslotL[act ? slot : 0];
        int p = i*(i-1)/2 + j;
        size_t eoff = ((size_t)(b*Nn + i)*Nn + j)*Ff + f;

        float z = 0.f, mo_f = 0.f, gs = 0.f, d2 = 0.f, wcf = 0.f;
        float wb = 0.f;
        float4 u[8];
        if (act) {
          const float4* u4 = (const float4*)&a.u_z[(((size_t)i*Nn + j)*Ff + f)*Ff];
#pragma unroll
          for (int q=0;q<8;++q) u[q] = u4[q];
          wb  = a.wzxb[eoff];
          wcf = a.wcxb[eoff];
          float wbmS = a.wbmax[p*8 + b];
          float unfS = a.unfmax[p];
          // z = sigmoid(wb + u . (agg - M[i,j]))
          const float4* ag4 = (const float4*)aggL;
          const float4* mj4 = (const float4*)Mc[jslot];
          float d = 0.f;
#pragma unroll
          for (int q=0;q<8;++q){
            float4 ag = ag4[q], mm = mj4[q];
            float mx = ag.x - mm.x, my = ag.y - mm.y;
            float mz = ag.z - mm.z, mw = ag.w - mm.w;
            d = fmaf(u[q].x,mx,d); d = fmaf(u[q].y,my,d);
            d = fmaf(u[q].z,mz,d); d = fmaf(u[q].w,mw,d);
          }
          z = sigmoidf_(wb + d);
          mo_f = aggL[f] - Mc[jslot][f];
          // scalar per-j screen (conservative vs per-(f,k): wb_f+un_f*n <= wbmS+unfS*n)
          if (wbmS + unfS*nmx >= 15.5f) {
            for (int s = 0; s < nn; ++s) {
              if (s == jslot) continue;                    // k == j
              if (wbmS + unfS*normC[s] < 15.5f) continue;  // scalar per-k screen
              float v = wb + dot32(u, Mc[s]);
              if (v >= 16.0f && (v > 17.5f || sigmoidf_(v) >= 1.0f))
                gs += Mc[s][f];
            }
          }
        }
        unsigned long long gb = __ballot(gs != 0.0f);
        bool rf = ((gb >> h32) & 0xFFFFFFFFull) != 0ull;
        if (rf) {
          float4 uc[8];
          const float4* uc4 = (const float4*)&a.u_c[(((size_t)i*Nn + j)*Ff + f)*Ff];
#pragma unroll
          for (int q=0;q<8;++q) uc[q]=uc4[q];
          float rm = 0.f;
#pragma unroll
          for (int g = 0; g < 32; ++g)
            rm = fmaf(VCE(uc,g), __shfl(gs, h32 + g), rm);
          float dd2 = 0.f;
#pragma unroll
          for (int g = 0; g < 32; ++g)
            dd2 = fmaf(VCE(uc,g), __shfl(rm, h32 + g), dd2);
          d2 = dd2;
        }
        if (act) {
          float cur = tanhf(wcf + d2);
          float mfv = (1.0f - z)*mo_f + z*cur;
          mfW[eoff] = mfv;
          float ss = mfv*mfv;
          ss += __shfl_xor(ss,1); ss += __shfl_xor(ss,2); ss += __shfl_xor(ss,4);
          ss += __shfl_xor(ss,8); ss += __shfl_xor(ss,16);
          if (f == 0) nrW[p*8 + b] = sqrtf(ss);
        }
      }
    }
    __threadfence();
    grid.sync();
    const float* tm = mfR; mfR = mfW; mfW = (float*)tm;
    const float* tn = nrR; nrR = nrW; nrW = (float*)tn;
  }

  // ======= Phase F: msg_sum gather + enc = relu(u_node.x + u_msg.msg) =======
  for (int task = gw; task < Bb*Nn; task += ngw) {
    int b = task >> 6, i = task & 63;
    const float* Ar = a.A + (size_t)(b*Nn + i)*Nn;
    if (h == 0) {
      float acc = 0.f;
#pragma unroll 8
      for (int k = 0; k < Nn; ++k) {
        int hi = i > k ? i : k, lo = i > k ? k : i;
        float av = Ar[k];
        float v = mfR[((size_t)(b*Nn + hi)*Nn + lo)*Ff + f];
        acc = fmaf(av, v, acc);    // a==0 terms exact no-ops (reference order)
      }
      vecF[w][1][f] = acc;
    } else {
      vecF[w][0][f] = a.x[(b*Nn + i)*Ff + f];
    }
    const float* Urow = (h == 0) ? &a.u_node[((size_t)i*Ff + f)*Ff]
                                 : &a.u_msg [((size_t)i*Ff + f)*Ff];
    const float4* w4 = (const float4*)Urow;
    float4 wr[8];
#pragma unroll
    for (int q=0;q<8;++q) wr[q]=w4[q];
    float d = dot32(wr, vecF[w][h]);
    float dO = __shfl(d, l ^ 32);
    if (l < 32) a.enc[(b*Nn + i)*Ff + f] = fmaxf(d + dO, 0.0f);
  }
  __threadfence();
  grid.sync();

  // ================= Phase L: output linear + sigmoid =================
  for (int task = gw; task < Bb*OUTn; task += ngw) {
    int b = task >> 7, o = task & 127;
    const float4* w4 = (const float4*)&a.lin_w[(size_t)o*(Nn*Ff)];
    const float4* e4 = (const float4*)&a.enc[(size_t)b*(Nn*Ff)];
    float acc = 0.f;
#pragma unroll
    for (int q = 0; q < 8; ++q) {
      float4 ww = w4[q*64 + l], ee = e4[q*64 + l];
      acc = fmaf(ww.x,ee.x,acc); acc = fmaf(ww.y,ee.y,acc);
      acc = fmaf(ww.z,ee.z,acc); acc = fmaf(ww.w,ee.w,acc);
    }
    acc += __shfl_xor(acc, 1);  acc += __shfl_xor(acc, 2);
    acc += __shfl_xor(acc, 4);  acc += __shfl_xor(acc, 8);
    acc += __shfl_xor(acc, 16); acc += __shfl_xor(acc, 32);
    if (l == 0) a.out[b*OUTn + o] = sigmoidf_(acc + a.lin_b[o]);
  }
}

extern "C" void kernel_launch(void* const* d_in, const int* in_sizes, int n_in,
                              void* d_out, int out_size, void* d_ws, size_t ws_size,
                              hipStream_t stream) {
  float* ws = (float*)d_ws;
  const size_t SZ = (size_t)Bb*Nn*Nn*Ff;      // 1,048,576 floats

  MegaArgs ha;
  ha.x      = (const float*)d_in[0];
  ha.A      = (const float*)d_in[1];
  ha.w_z    = (const float*)d_in[2];
  ha.w_c    = (const float*)d_in[3];
  ha.u_z    = (const float*)d_in[4];
  ha.u_c    = (const float*)d_in[5];
  ha.b_z    = (const float*)d_in[6];
  ha.b_c    = (const float*)d_in[7];
  ha.u_node = (const float*)d_in[8];
  ha.u_msg  = (const float*)d_in[9];
  ha.lin_w  = (const float*)d_in[10];
  ha.lin_b  = (const float*)d_in[11];
  ha.out    = (float*)d_out;
  ha.wzxb   = ws;
  ha.wcxb   = ha.wzxb + SZ;
  ha.mf0    = ha.wcxb + SZ;
  ha.mf1    = ha.mf0  + SZ;
  ha.nrm0   = ha.mf1  + SZ;                   // NPAIR*8
  ha.nrm1   = ha.nrm0 + (size_t)NPAIR*8;
  ha.unfmax = ha.nrm1 + (size_t)NPAIR*8;      // NPAIR
  ha.wbmax  = ha.unfmax + NPAIR;              // NPAIR*8
  ha.enc    = ha.wbmax + (size_t)NPAIR*8;     // 8*64*32

  int occ = 0;
  hipOccupancyMaxActiveBlocksPerMultiprocessor(&occ, (const void*)mega, 256, 0);
  if (occ < 1) occ = 1;
  long long cap = (long long)occ * 256;       // 256 CUs on MI355X
  int gridN = cap > 1024 ? 1024 : (int)cap;

  void* kargs[] = { (void*)&ha };
  hipLaunchCooperativeKernel((const void*)mega, dim3(gridN), dim3(256),
                             kargs, 0, stream);
}

// Round 10
// 289.914 us; speedup vs baseline: 2.2236x; 2.2236x over previous
//
#include <hip/hip_runtime.h>
#include <math.h>

#define Bb 8
#define Nn 64
#define Ff 32
#define Tt 4
#define OUTn 128
#define NPAIR 2016   // 64*63/2 lower-triangle pairs (i>j)

__device__ __forceinline__ float sigmoidf_(float x){ return 1.0f/(1.0f+expf(-x)); }

__device__ __forceinline__ void p2ij(int p, int& i, int& j){
  int ii = (int)((1.0f + sqrtf(1.0f + 8.0f*(float)p)) * 0.5f);
  while (ii*(ii-1)/2 > p) --ii;
  while ((ii+1)*ii/2 <= p) ++ii;
  i = ii; j = p - ii*(ii-1)/2;
}

// sequential-order fp32 dot (bit-identical to the validated round-0 ordering;
// the floor(sigmoid) gate is discontinuous -> this order must not change)
__device__ __forceinline__ float dot32(const float4* __restrict__ u, const float* __restrict__ v){
  const float4* v4 = (const float4*)v;
  float d = 0.f;
#pragma unroll
  for (int q=0;q<8;++q){
    float4 a=u[q], b=v4[q];
    d = fmaf(a.x,b.x,d); d = fmaf(a.y,b.y,d);
    d = fmaf(a.z,b.z,d); d = fmaf(a.w,b.w,d);
  }
  return d;
}

#define VCE(arr,g) ((g&3)==0 ? arr[(g)>>2].x : (g&3)==1 ? arr[(g)>>2].y : \
                    (g&3)==2 ? arr[(g)>>2].z : arr[(g)>>2].w)

// ---- precompute (pair-major): wz/wc[p][b][f], fused t=0 mf0, wbmax, unfmax ----
__global__ __launch_bounds__(64) void precompute_pair(
    const float* __restrict__ x,
    const float* __restrict__ w_z,
    const float* __restrict__ w_c,
    const float* __restrict__ u_z,
    const float* __restrict__ b_z,
    const float* __restrict__ b_c,
    float* __restrict__ wz,
    float* __restrict__ wc,
    float* __restrict__ mf0,
    float* __restrict__ wbmax,
    float* __restrict__ unfmax) {
  int p = blockIdx.x;
  int i, j; p2ij(p, i, j);
  int l = threadIdx.x, f = l & 31, h = l >> 5;

  __shared__ __align__(16) float xL[Bb][Ff];
  __shared__ __align__(16) float valL[2][Bb][Ff];
  for (int q = l; q < Bb*Ff; q += 64) {
    int b = q >> 5, g = q & 31;
    xL[b][g] = x[(b*Nn + i)*Ff + g];
  }
  __syncthreads();

  const float* W = h ? w_c : w_z;
  const float4* w4 = (const float4*)&W[(((size_t)i*Nn + j)*Ff + f)*Ff];
  float4 wr[8];
#pragma unroll
  for (int q=0;q<8;++q) wr[q]=w4[q];
  float bias = h ? b_c[f] : b_z[f];
  float* dst = h ? wc : wz;
#pragma unroll
  for (int b=0;b<Bb;++b){
    float v = dot32(wr, xL[b]) + bias;
    dst[(size_t)p*256 + b*32 + f] = v;
    valL[h][b][f] = v;
    if (h == 0) {         // wbmax[p,b] = max_f wzxb
      float wm = v;
      wm = fmaxf(wm, __shfl_xor(wm,1));  wm = fmaxf(wm, __shfl_xor(wm,2));
      wm = fmaxf(wm, __shfl_xor(wm,4));  wm = fmaxf(wm, __shfl_xor(wm,8));
      wm = fmaxf(wm, __shfl_xor(wm,16));
      if (f == 0) wbmax[p*8 + b] = wm;
    }
  }
  __syncthreads();
  // t=0: M=0 -> gated_sum=0, r_msg=0 -> m_full0 = sigmoid(wz)*tanh(wc) (bit-exact)
  if (h == 0) {
#pragma unroll
    for (int b=0;b<Bb;++b)
      mf0[(size_t)p*256 + b*32 + f] =
          sigmoidf_(valL[0][b][f]) * tanhf(valL[1][b][f]);
  } else {
    // unfmax[p] = max_f ||u_z[i,j,f,:]||
    const float4* u4 = (const float4*)&u_z[(((size_t)i*Nn + j)*Ff + f)*Ff];
    float ss = 0.f;
#pragma unroll
    for (int q=0;q<8;++q){
      float4 v = u4[q];
      ss = fmaf(v.x,v.x,ss); ss = fmaf(v.y,v.y,ss);
      ss = fmaf(v.z,v.z,ss); ss = fmaf(v.w,v.w,ss);
    }
    ss = fmaxf(ss, __shfl_xor(ss,1));  ss = fmaxf(ss, __shfl_xor(ss,2));
    ss = fmaxf(ss, __shfl_xor(ss,4));  ss = fmaxf(ss, __shfl_xor(ss,8));
    ss = fmaxf(ss, __shfl_xor(ss,16));
    if (f == 0) unfmax[p] = sqrtf(ss);
  }
}

// ---- one MP iteration (t>=1): block=(bh, i, jq); 4 b's folded per block so
//      each u_z row is loaded ONCE into regs and reused 4x (MLP + traffic fix) ----
__global__ __launch_bounds__(512) void edge_update(
    const float* __restrict__ A,
    const float* __restrict__ u_z,
    const float* __restrict__ u_c,
    const float* __restrict__ wz,
    const float* __restrict__ wc,
    const float* __restrict__ wbmax,
    const float* __restrict__ unfmax,
    const float* __restrict__ mfp,
    float* __restrict__ mfn) {
  int bh = blockIdx.x;   // 2 (b-half)
  int i  = blockIdx.y;   // 64
  int jq = blockIdx.z;   // 4
  if (i <= jq) return;   // uniform: smallest j of this block is jq
  int tid = threadIdx.x; // 512
  int f = tid & 31;
  int hw = tid >> 5;     // half-wave (j-slot) 0..15
  int h32 = tid & 32;

  __shared__ __align__(16) float Mc[4][Nn][Ff];   // 32 KB, k-indexed
  __shared__ __align__(16) float aggL[4][Ff];
  __shared__ float normC[4][Nn];
  __shared__ float nmaxL[4];
  __shared__ unsigned long long kadjL[4];

  // adjacency masks: wave wv handles bl=wv
  {
    int wv = tid >> 6, l = tid & 63;
    if (wv < 4) {
      float av = A[((bh*4 + wv)*Nn + i)*Nn + l];
      unsigned long long m = __ballot(av != 0.0f);
      if (l == 0) kadjL[wv] = m;
    }
  }
  __syncthreads();

  // prefetch this slot's u_z row (latency hides under staging)
  int j = hw*4 + jq;
  bool act = (j < i);
  int p = act ? (i*(i-1)/2 + j) : 0;
  float4 u[8];
  if (act) {
    const float4* u4 = (const float4*)&u_z[(((size_t)i*Nn + j)*Ff + f)*Ff];
#pragma unroll
    for (int q=0;q<8;++q) u[q] = u4[q];
  } else {
#pragma unroll
    for (int q=0;q<8;++q) u[q] = make_float4(0.f,0.f,0.f,0.f);
  }

  // stage edge rows (coalesced 128B per half-wave) + norms for free
  for (int it = hw; it < 4*Nn; it += 16) {
    int bl = it >> 6, k = it & 63;
    if ((kadjL[bl] >> k) & 1ull) {
      int b = bh*4 + bl;
      int hi = i > k ? i : k, lo = i > k ? k : i;
      int pk = hi*(hi-1)/2 + lo;
      float v = mfp[(size_t)pk*256 + b*32 + f];
      Mc[bl][k][f] = v;
      float ss = v*v;
      ss += __shfl_xor(ss,1); ss += __shfl_xor(ss,2); ss += __shfl_xor(ss,4);
      ss += __shfl_xor(ss,8); ss += __shfl_xor(ss,16);
      if (f == 0) normC[bl][k] = sqrtf(ss);
    }
  }
  __syncthreads();

  if (hw < 4) {          // agg: ascending edge-only serial sum (validated order)
    int bl = hw;
    float acc = 0.f;
    unsigned long long kk = kadjL[bl];
    while (kk) {
      int k = __builtin_ctzll(kk); kk &= kk - 1;
      acc += Mc[bl][k][f];
    }
    aggL[bl][f] = acc;
  } else if (hw < 8) {   // nmax per bl
    int bl = hw - 4;
    unsigned long long kk = kadjL[bl];
    float m = ((kk >> f) & 1ull) ? normC[bl][f] : 0.f;
    if ((kk >> (f+32)) & 1ull) m = fmaxf(m, normC[bl][f+32]);
    m = fmaxf(m, __shfl_xor(m,1));  m = fmaxf(m, __shfl_xor(m,2));
    m = fmaxf(m, __shfl_xor(m,4));  m = fmaxf(m, __shfl_xor(m,8));
    m = fmaxf(m, __shfl_xor(m,16));
    if (f == 0) nmaxL[bl] = m;
  }
  __syncthreads();

  if (!act) return;      // after all barriers

  float unf = unfmax[p];
  float un = 0.f;        // per-f ||u row|| (tight ballot screen, validated r4)
#pragma unroll
  for (int q=0;q<8;++q){
    float4 aa = u[q];
    un = fmaf(aa.x,aa.x,un); un = fmaf(aa.y,aa.y,un);
    un = fmaf(aa.z,aa.z,un); un = fmaf(aa.w,aa.w,un);
  }
  un = sqrtf(un);

  for (int bl = 0; bl < 4; ++bl) {
    unsigned long long kadj = kadjL[bl];
    if (!((kadj >> j) & 1ull)) continue;   // half-wave-uniform
    int b = bh*4 + bl;
    size_t pb = (size_t)p*256 + b*32;
    float wb  = wz[pb + f];
    float wcf = wc[pb + f];
    // z = sigmoid(wb + u . (agg - M[i,j]))   (validated fused form)
    const float* Mj = Mc[bl][j];
    const float4* ag4 = (const float4*)aggL[bl];
    const float4* mj4 = (const float4*)Mj;
    float d = 0.f;
#pragma unroll
    for (int q=0;q<8;++q){
      float4 ag = ag4[q], mm = mj4[q];
      float mx = ag.x - mm.x, my = ag.y - mm.y;
      float mz = ag.z - mm.z, mw = ag.w - mm.w;
      d = fmaf(u[q].x,mx,d); d = fmaf(u[q].y,my,d);
      d = fmaf(u[q].z,mz,d); d = fmaf(u[q].w,mw,d);
    }
    float z = sigmoidf_(wb + d);
    float mo = aggL[bl][f] - Mj[f];

    float gs = 0.f;
    float wbm = wbmax[p*8 + b];
    if (wbm + unf*nmaxL[bl] >= 15.5f) {        // scalar per-j screen
      unsigned long long kk = kadj & ~(1ull << j);
      while (kk) {
        int k = __builtin_ctzll(kk); kk &= kk - 1;
        float nk = normC[bl][k];
        if (wbm + unf*nk < 15.5f) continue;    // scalar per-k screen
        unsigned long long sb = __ballot(wb + un*nk >= 15.5f);
        if (((sb >> h32) & 0xFFFFFFFFull) == 0ull) continue;  // per-f screen
        float v = wb + dot32(u, Mc[bl][k]);    // exact gate dot (fixed order)
        if (v >= 16.0f && (v > 17.5f || sigmoidf_(v) >= 1.0f))
          gs += Mc[bl][k][f];
      }
    }

    // rare fire path: u_c dots via in-half shuffles (validated r7)
    float d2 = 0.f;
    unsigned long long gb = __ballot(gs != 0.0f);
    if (((gb >> h32) & 0xFFFFFFFFull) != 0ull) {
      float4 uc[8];
      const float4* uc4 = (const float4*)&u_c[(((size_t)i*Nn + j)*Ff + f)*Ff];
#pragma unroll
      for (int q=0;q<8;++q) uc[q]=uc4[q];
      float rm = 0.f;
#pragma unroll
      for (int g = 0; g < 32; ++g)
        rm = fmaf(VCE(uc,g), __shfl(gs, h32 + g), rm);
      float dd2 = 0.f;
#pragma unroll
      for (int g = 0; g < 32; ++g)
        dd2 = fmaf(VCE(uc,g), __shfl(rm, h32 + g), dd2);
      d2 = dd2;
    }

    float cur = tanhf(wcf + d2);
    mfn[pb + f] = (1.0f - z)*mo + z*cur;
  }
}

// ---- msg_sum gather + enc = relu(u_node.x + u_msg.msg_sum)  (r6, validated) ----
__global__ __launch_bounds__(64) void finalize_enc(
    const float* __restrict__ x,
    const float* __restrict__ A,
    const float* __restrict__ mf,
    const float* __restrict__ u_node,
    const float* __restrict__ u_msg,
    float* __restrict__ enc) {
  int bi = blockIdx.x;
  int b = bi >> 6, i = bi & 63;
  int l = threadIdx.x, f = l & 31, h = l >> 5;

  float a = A[(b*Nn + i)*Nn + l];
  unsigned long long mask = __ballot(a != 0.0f);
  float acc = 0.f;
  unsigned long long mm = mask;
  int idx = 0;
  while (mm) {
    int k = __builtin_ctzll(mm);
    mm &= mm - 1;
    if ((idx & 1) == h) {
      int hi = i > k ? i : k, lo = i > k ? k : i;
      acc += mf[(size_t)(hi*(hi-1)/2 + lo)*256 + b*32 + f];
    }
    idx++;
  }
  float accO = __shfl(acc, l ^ 32);
  acc += accO;

  __shared__ __align__(16) float vecL[2][Ff];
  if (l < 32) { vecL[0][l] = x[(b*Nn + i)*Ff + l]; vecL[1][l] = acc; }
  __syncthreads();
  const float* Urow = (h == 0) ? &u_node[((size_t)i*Ff + f)*Ff]
                               : &u_msg [((size_t)i*Ff + f)*Ff];
  const float4* w4 = (const float4*)Urow;
  float4 w[8];
#pragma unroll
  for (int q=0;q<8;++q) w[q]=w4[q];
  float d = dot32(w, vecL[h]);
  float dO = __shfl(d, l ^ 32);
  if (l < 32) enc[(b*Nn + i)*Ff + f] = fmaxf(d + dO, 0.0f);
}

// ---- output linear + sigmoid: one wave per (b, o) (validated r4) ----
__global__ __launch_bounds__(64) void linear_out(
    const float* __restrict__ enc,
    const float* __restrict__ lin_w,
    const float* __restrict__ lin_b,
    float* __restrict__ out) {
  int b = blockIdx.x >> 7;
  int o = blockIdx.x & 127;
  int l = threadIdx.x;
  const float4* w4 = (const float4*)&lin_w[(size_t)o*(Nn*Ff)];
  const float4* e4 = (const float4*)&enc[(size_t)b*(Nn*Ff)];
  float acc = 0.f;
#pragma unroll
  for (int q = 0; q < 8; ++q) {
    float4 w = w4[q*64 + l], e = e4[q*64 + l];
    acc = fmaf(w.x,e.x,acc); acc = fmaf(w.y,e.y,acc);
    acc = fmaf(w.z,e.z,acc); acc = fmaf(w.w,e.w,acc);
  }
  acc += __shfl_xor(acc, 1);  acc += __shfl_xor(acc, 2);
  acc += __shfl_xor(acc, 4);  acc += __shfl_xor(acc, 8);
  acc += __shfl_xor(acc, 16); acc += __shfl_xor(acc, 32);
  if (l == 0) out[b*OUTn + o] = sigmoidf_(acc + lin_b[o]);
}

extern "C" void kernel_launch(void* const* d_in, const int* in_sizes, int n_in,
                              void* d_out, int out_size, void* d_ws, size_t ws_size,
                              hipStream_t stream) {
  const float* x      = (const float*)d_in[0];
  const float* A      = (const float*)d_in[1];
  const float* w_z    = (const float*)d_in[2];
  const float* w_c    = (const float*)d_in[3];
  const float* u_z    = (const float*)d_in[4];
  const float* u_c    = (const float*)d_in[5];
  const float* b_z    = (const float*)d_in[6];
  const float* b_c    = (const float*)d_in[7];
  const float* u_node = (const float*)d_in[8];
  const float* u_msg  = (const float*)d_in[9];
  const float* lin_w  = (const float*)d_in[10];
  const float* lin_b  = (const float*)d_in[11];
  float* out = (float*)d_out;
  float* ws  = (float*)d_ws;

  const size_t PB = (size_t)NPAIR * 256;      // 516096 floats
  float* wz     = ws;
  float* wc     = wz   + PB;
  float* mf0    = wc   + PB;
  float* mf1    = mf0  + PB;
  float* wbmax  = mf1  + PB;                  // NPAIR*8
  float* unfmax = wbmax + (size_t)NPAIR*8;    // NPAIR
  float* enc    = unfmax + NPAIR;             // 8*64*32

  precompute_pair<<<NPAIR, 64, 0, stream>>>(x, w_z, w_c, u_z, b_z, b_c,
                                            wz, wc, mf0, wbmax, unfmax);

  const float* mfR = mf0; float* mfW = mf1;
  for (int t = 1; t < Tt; ++t) {
    edge_update<<<dim3(2, Nn, 4), 512, 0, stream>>>(A, u_z, u_c, wz, wc,
                                                    wbmax, unfmax, mfR, mfW);
    float* tm = (float*)mfR; mfR = mfW; mfW = tm;
  }
  finalize_enc<<<Bb*Nn, 64, 0, stream>>>(x, A, mfR, u_node, u_msg, enc);
  linear_out<<<Bb*OUTn, 64, 0, stream>>>(enc, lin_w, lin_b, out);
}